// Round 17
// baseline (141.373 us; speedup 1.0000x reference)
//
#include <hip/hip_runtime.h>
#include <hip/hip_fp16.h>
#include <math.h>

// Capsule dynamic routing, fused-recompute. fp32 accumulate, f16 data.
// B=512, R=1152, C=10, O=16, I=8.
//   iter0: c_ij = 1/10 uniform  -> s0 = 0.1 * sum_r u_hat
//   iter2: b2 = u.(v0+v1)       -> only running vsum kept
// R16 post-mortem: NaN fail; changed grid AND partial dtype at once
// (rule violation), bug not localizable by inspection -> revert both.
// R17 = R15's proven f16 body/stores verbatim + RT=96 constants only:
// grid 768 = exactly 3 blocks/CU (12 waves/CU, 1.5x R15's TLP), RCHB=12
// as 3 double-buffered chunks of 4 (20KB LDS), fp32 partials 31.4MB
// (R12 measured FETCH 25.8MB = ideal at this footprint -> no L2 thrash),
// f16 xt 9.4MB; ws 40.8MB. R12's proven xcd*12 rtile mapping.

#define R_TOT 1152
#define C_N 10
#define O_N 16
#define I_N 8
#define B_TOT 512
#define RT 96                                   // rtile count (partial slices)
#define RCHB 12                                 // r's per block
#define CHUNK 4                                 // r's per staged chunk
#define NCH 3                                   // chunks per block
#define SEG (B_TOT * C_N * O_N)                 // 81920 floats per partial slice
#define ROWS (C_N * O_N)                        // 160 W rows per r (16B each in f16)
#define CGR (CHUNK * ROWS)                      // 640 rows per chunk

typedef _Float16 h2 __attribute__((ext_vector_type(2)));

// pack two fp32 -> f16x2 (RTN via __float2half)
__device__ __forceinline__ unsigned packf2(float a, float b) {
  unsigned ua = (unsigned)__half_as_ushort(__float2half(a));
  unsigned ub = (unsigned)__half_as_ushort(__float2half(b));
  return ua | (ub << 16);
}

// acc += dot2(w, x) in fp32
__device__ __forceinline__ float dot2acc(unsigned w, unsigned x, float acc) {
#if __has_builtin(__builtin_amdgcn_fdot2)
  return __builtin_amdgcn_fdot2(__builtin_bit_cast(h2, w),
                                __builtin_bit_cast(h2, x), acc, false);
#else
  h2 hw = __builtin_bit_cast(h2, w), hx = __builtin_bit_cast(h2, x);
  return acc + (float)hw[0] * (float)hx[0] + (float)hw[1] * (float)hx[1];
#endif
}

// quad_perm DPP cross-lane adds (VALU pipe, not LDS): xor1 / xor2 over oq.
__device__ __forceinline__ float quad_add1(float v) {
  return v + __int_as_float(__builtin_amdgcn_update_dpp(
      0, __float_as_int(v), 0xB1 /*[1,0,3,2]*/, 0xF, 0xF, true));
}
__device__ __forceinline__ float quad_add2(float v) {
  return v + __int_as_float(__builtin_amdgcn_update_dpp(
      0, __float_as_int(v), 0x4E /*[2,3,0,1]*/, 0xF, 0xF, true));
}

// x[b][r][i] fp32 -> xt[r][b] as 8 packed f16 (one uint4)
__global__ __launch_bounds__(256) void transpose_x(
    const float* __restrict__ x, uint4* __restrict__ xt)
{
  const int t = blockIdx.x * 256 + threadIdx.x;   // t = b*R_TOT + r
  const int b = t / R_TOT;
  const int r = t - b * R_TOT;
  const float4* src = reinterpret_cast<const float4*>(x) + (size_t)t * 2;
  const float4 a = src[0], c = src[1];
  uint4 o;
  o.x = packf2(a.x, a.y); o.y = packf2(a.z, a.w);
  o.z = packf2(c.x, c.y); o.w = packf2(c.z, c.w);
  xt[(size_t)r * B_TOT + b] = o;
}

// one r-step: u = W.x for this thread's (5c x 4o x 2b), then routing update.
// W row (8 f16) = ONE ds_read_b128; 4 chained dot2 per u, fp32 acc.
template<bool UNIFORM>
__device__ __forceinline__ void body(
    const uint4* __restrict__ A16, int slabG,   // row offset (runtime)
    const uint4 (&xc)[2],
    const float (&vf)[5][2][4],
    float (&sacc)[5][2][4])
{
  float u[5][2][4];
  #pragma unroll
  for (int cc = 0; cc < 5; ++cc) {
    #pragma unroll
    for (int jo = 0; jo < 4; ++jo) {
      const uint4 w = A16[slabG + ((cc * 4 + jo) << 3)];
      #pragma unroll
      for (int k = 0; k < 2; ++k) {
        u[cc][k][jo] = dot2acc(w.x, xc[k].x,
                       dot2acc(w.y, xc[k].y,
                       dot2acc(w.z, xc[k].z,
                       dot2acc(w.w, xc[k].w, 0.0f))));
      }
    }
  }

  if constexpr (UNIFORM) {
    #pragma unroll
    for (int cc = 0; cc < 5; ++cc)
      #pragma unroll
      for (int k = 0; k < 2; ++k)
        #pragma unroll
        for (int jo = 0; jo < 4; ++jo)
          sacc[cc][k][jo] += u[cc][k][jo];
  } else {
    float bij[5][2];
    #pragma unroll
    for (int cc = 0; cc < 5; ++cc) {
      #pragma unroll
      for (int k = 0; k < 2; ++k) {
        float a = u[cc][k][0] * vf[cc][k][0] + u[cc][k][1] * vf[cc][k][1]
                + u[cc][k][2] * vf[cc][k][2] + u[cc][k][3] * vf[cc][k][3];
        a = quad_add1(a);        // + lane^1  (oq)
        a = quad_add2(a);        // + lane^2  (oq)
        bij[cc][k] = a;
      }
    }
    #pragma unroll
    for (int k = 0; k < 2; ++k) {
      float m = bij[0][k];
      #pragma unroll
      for (int cc = 1; cc < 5; ++cc) m = fmaxf(m, bij[cc][k]);
      m = fmaxf(m, __shfl_xor(m, 4));
      float e[5];
      float den = 0.0f;
      #pragma unroll
      for (int cc = 0; cc < 5; ++cc) { e[cc] = __expf(bij[cc][k] - m); den += e[cc]; }
      den += __shfl_xor(den, 4);
      const float inv = __builtin_amdgcn_rcpf(den);
      #pragma unroll
      for (int cc = 0; cc < 5; ++cc) {
        const float cw = e[cc] * inv;
        #pragma unroll
        for (int jo = 0; jo < 4; ++jo)
          sacc[cc][k][jo] += cw * u[cc][k][jo];
      }
    }
  }
}

// lane map: oq = lane&3, ch = (lane>>2)&1, bl = lane>>3; thread owns
// b0 = btile*64 + wave*16 + bl*2 (+k), c = ch*5+cc, o = oq*4+jo.
// grid 768: xcd = bid&7, idx = bid>>3 (0..95); rtile = xcd*12 + idx%12,
// btile = idx/12. Each XCD owns 12 contiguous rtiles.
template<bool UNIFORM>
__global__ __launch_bounds__(256, 2) void acc_kernel(
    const uint4* __restrict__ xt, const float* __restrict__ W,
    const float* __restrict__ vsum, float* __restrict__ part)
{
  __shared__ uint4 wbuf[2 * CGR];   // 20 KB: two 4-slab f16 chunks

  const int tid  = threadIdx.x;
  const int wave = tid >> 6;
  const int lane = tid & 63;
  const int oq   = lane & 3;
  const int ch   = (lane >> 2) & 1;
  const int bl   = lane >> 3;

  const int bid   = blockIdx.x;
  const int xcd   = bid & 7;
  const int idx   = bid >> 3;             // 0..95
  const int rtile = xcd * 12 + (idx % 12);
  const int btile = idx / 12;             // 0..7

  const int b0 = btile * 64 + wave * 16 + bl * 2;
  const int r0 = rtile * RCHB;

  // stage CHUNK W slabs as f16 rows; row (c,o) -> p=(cc*4+jo)*8+(ch*4+oq)
  auto stage = [&](int ci, int buf) {
    const int rbase = r0 + ci * CHUNK;
    #pragma unroll 1
    for (int g = tid; g < CGR; g += 256) {
      const int s   = g / ROWS;
      const int row = g - s * ROWS;
      const float4* wsrc = reinterpret_cast<const float4*>(W)
                         + ((size_t)(rbase + s) * ROWS + row) * 2;
      const float4 a = wsrc[0], c = wsrc[1];
      const int ci_  = row >> 4, o = row & 15;
      const int chr  = (ci_ >= 5) ? 1 : 0;
      const int ccr  = ci_ - chr * 5;
      const int p    = ((ccr * 4 + (o & 3)) << 3) | (chr * 4 + (o >> 2));
      uint4 v;
      v.x = packf2(a.x, a.y); v.y = packf2(a.z, a.w);
      v.z = packf2(c.x, c.y); v.w = packf2(c.z, c.w);
      wbuf[buf * CGR + s * ROWS + p] = v;
    }
  };

  auto xload = [&](int r, uint4 (&dst)[2]) {
    const uint4* xp = xt + (size_t)r * B_TOT + b0;
    dst[0] = xp[0];
    dst[1] = xp[1];
  };

  // per-thread LDS read base (row units); all (cc,jo) offsets compile-time
  const uint4* A16 = wbuf + (ch * 4 + oq);

  float vf[5][2][4];
  if constexpr (!UNIFORM) {
    #pragma unroll
    for (int cc = 0; cc < 5; ++cc)
      #pragma unroll
      for (int k = 0; k < 2; ++k) {
        const float4 tv = *reinterpret_cast<const float4*>(
            &vsum[((b0 + k) * C_N + ch * 5 + cc) * O_N + oq * 4]);
        vf[cc][k][0] = tv.x; vf[cc][k][1] = tv.y; vf[cc][k][2] = tv.z; vf[cc][k][3] = tv.w;
      }
  }

  float sacc[5][2][4];
  #pragma unroll
  for (int cc = 0; cc < 5; ++cc)
    #pragma unroll
    for (int k = 0; k < 2; ++k)
      #pragma unroll
      for (int jo = 0; jo < 4; ++jo) sacc[cc][k][jo] = 0.0f;

  uint4 xc[2], xn[2];
  stage(0, 0);
  xload(r0, xc);
  __syncthreads();

  #pragma unroll 1
  for (int ci = 0; ci < NCH; ++ci) {
    if (ci + 1 < NCH) stage(ci + 1, (ci + 1) & 1);
    const int sb = (ci & 1) * CGR;
    #pragma unroll 2
    for (int rr = 0; rr < CHUNK; ++rr) {
      const int rl = ci * CHUNK + rr;
      const int rn = (rl + 1 < RCHB) ? rl + 1 : rl;
      xload(r0 + rn, xn);                 // prefetch next x under compute
      body<UNIFORM>(A16, sb + rr * ROWS, xc, vf, sacc);
      xc[0] = xn[0]; xc[1] = xn[1];
    }
    __syncthreads();
  }

  // fp32 float4 partial store (R15-proven path)
  const float scale = UNIFORM ? 0.1f : 1.0f;
  float* pb = part + (size_t)rtile * SEG;
  #pragma unroll
  for (int cc = 0; cc < 5; ++cc)
    #pragma unroll
    for (int k = 0; k < 2; ++k) {
      float4 v;
      v.x = sacc[cc][k][0] * scale; v.y = sacc[cc][k][1] * scale;
      v.z = sacc[cc][k][2] * scale; v.w = sacc[cc][k][3] * scale;
      *reinterpret_cast<float4*>(
          &pb[((b0 + k) * C_N + ch * 5 + cc) * O_N + oq * 4]) = v;
    }
}

// reduce over rtiles + squash over O=16 per (b,c). grid = SEG/64 blocks.
// MODE 0: vsum = v ; MODE 1: vsum += v ; MODE 2: out = v
template<int MODE>
__global__ __launch_bounds__(256) void reduce_squash(
    const float* __restrict__ part, int nrt,
    float* __restrict__ vsum, float* __restrict__ out)
{
  __shared__ float lds[4][64];
  const int tid = threadIdx.x;
  const int l   = tid & 63;
  const int q   = tid >> 6;
  const int j   = blockIdx.x * 64 + l;
  const float* p = part + j;
  float sv = 0.0f;
  #pragma unroll 4
  for (int rt = q; rt < nrt; rt += 4) sv += p[(size_t)rt * SEG];
  lds[q][l] = sv;
  __syncthreads();
  if (q == 0) {
    sv = lds[0][l] + lds[1][l] + lds[2][l] + lds[3][l];
    float sq = sv * sv;
    sq += __shfl_xor(sq, 1);
    sq += __shfl_xor(sq, 2);
    sq += __shfl_xor(sq, 4);
    sq += __shfl_xor(sq, 8);
    const float scale = sq / (1.0f + sq) * rsqrtf(sq + 1e-8f);
    const float v = scale * sv;
    if constexpr (MODE == 0)      vsum[j] = v;
    else if constexpr (MODE == 1) vsum[j] += v;
    else                          out[j] = v;
  }
}

extern "C" void kernel_launch(void* const* d_in, const int* in_sizes, int n_in,
                              void* d_out, int out_size, void* d_ws, size_t ws_size,
                              hipStream_t stream) {
  (void)in_sizes; (void)n_in; (void)out_size; (void)ws_size;
  const float* x = (const float*)d_in[0];
  const float* W = (const float*)d_in[1];
  float* out  = (float*)d_out;   // doubles as vsum; fully rewritten with v2
  float* part = (float*)d_ws;    // RT * SEG floats = 31.4 MB
  uint4* xt   = reinterpret_cast<uint4*>(part + (size_t)RT * SEG);  // 9.4 MB f16

  const dim3 blk(256), accGrid(8 * RT), sqGrid(SEG / 64);

  hipLaunchKernelGGL(transpose_x, dim3((B_TOT * R_TOT) / 256), blk, 0, stream, x, xt);

  // iter 0: uniform coefficients (softmax of zeros)
  hipLaunchKernelGGL((acc_kernel<true>),  accGrid, blk, 0, stream, xt, W, out, part);
  hipLaunchKernelGGL((reduce_squash<0>),  sqGrid,  blk, 0, stream, part, RT, out, out);  // vsum = v0
  // iter 1
  hipLaunchKernelGGL((acc_kernel<false>), accGrid, blk, 0, stream, xt, W, out, part);
  hipLaunchKernelGGL((reduce_squash<1>),  sqGrid,  blk, 0, stream, part, RT, out, out);  // vsum = v0+v1
  // iter 2
  hipLaunchKernelGGL((acc_kernel<false>), accGrid, blk, 0, stream, xt, W, out, part);
  hipLaunchKernelGGL((reduce_squash<2>),  sqGrid,  blk, 0, stream, part, RT, out, out);  // out = v2
}

// Round 18
// 118.427 us; speedup vs baseline: 1.1938x; 1.1938x over previous
//
#include <hip/hip_runtime.h>
#include <hip/hip_fp16.h>
#include <math.h>

// Capsule dynamic routing, fused-recompute. MFMA einsum, f16 data, fp32 acc.
// B=512, R=1152, C=10, O=16, I=8.
//   iter0: c_ij = 1/10 uniform  -> s0 = 0.1 * sum_r u_hat
//   iter2: b2 = u.(v0+v1)       -> only running vsum kept
// R17 post-mortem: 3 blocks/CU regressed (occupancy stuck ~16%); TLP
// lever dead. R15 accounting: VALU 20.5us (160 v_dot2/iter) is the top
// term while MfmaUtil=0 on a matmul-shaped kernel.
// R18 = R15 frozen except the einsum -> v_mfma_f32_16x16x32_f16:
// D[co16, b16] = Wtile . x, K=8 real (zero-padded). Lane roles:
// bq=lane&15 (b), og=lane>>4 (o-quad); C/D layout m89-verified
// (col=lane&15, row=og*4+reg). A/B k-map: doubled-K16 layout
// (regs[0:3] k=og*4+j, regs[4:7] k=16+og*4+j) per m156/m162 evidence:
// og 0/1 lanes carry the real 8B, og 2/3 zero. LDS now LINEAR (no
// permute; masked b64 reads conflict-free by construction). Routing =
// same math, o-reduce via shfl_xor 16/32, softmax fully lane-local.

#define R_TOT 1152
#define C_N 10
#define O_N 16
#define I_N 8
#define B_TOT 512
#define RT 64                                   // rtile count (partial slices)
#define RCHB 18                                 // r's per block
#define CHUNK 6                                 // r's per staged chunk
#define NCH 3                                   // chunks per block
#define SEG (B_TOT * C_N * O_N)                 // 81920 floats per partial slice
#define ROWS (C_N * O_N)                        // 160 W rows per r (16B each, f16)
#define CGR (CHUNK * ROWS)                      // 960 rows per chunk

typedef _Float16 v8h __attribute__((ext_vector_type(8)));
typedef float v4f __attribute__((ext_vector_type(4)));
typedef unsigned u32x4 __attribute__((ext_vector_type(4)));

// pack two fp32 -> f16x2 (RTN via __float2half)
__device__ __forceinline__ unsigned packf2(float a, float b) {
  unsigned ua = (unsigned)__half_as_ushort(__float2half(a));
  unsigned ub = (unsigned)__half_as_ushort(__float2half(b));
  return ua | (ub << 16);
}

// x[b][r][i] fp32 -> xt[r][b] as 8 packed f16 (one uint4)
__global__ __launch_bounds__(256) void transpose_x(
    const float* __restrict__ x, uint4* __restrict__ xt)
{
  const int t = blockIdx.x * 256 + threadIdx.x;   // t = b*R_TOT + r
  const int b = t / R_TOT;
  const int r = t - b * R_TOT;
  const float4* src = reinterpret_cast<const float4*>(x) + (size_t)t * 2;
  const float4 a = src[0], c = src[1];
  uint4 o;
  o.x = packf2(a.x, a.y); o.y = packf2(a.z, a.w);
  o.z = packf2(c.x, c.y); o.w = packf2(c.z, c.w);
  xt[(size_t)r * B_TOT + b] = o;
}

// lane map: bq = lane&15 (b within wave's 16), og = lane>>4 (o-quad).
// thread's b = btile*64 + wave*16 + bq; it holds u[c][o=og*4+j] for all c.
// grid 512: xcd = bid&7, idx = bid>>3; rtile = xcd*8+(idx&7), btile = idx>>3.
template<bool UNIFORM>
__global__ __launch_bounds__(256, 2) void acc_kernel(
    const uint4* __restrict__ xt, const float* __restrict__ W,
    const float* __restrict__ vsum, float* __restrict__ part)
{
  __shared__ uint4 wbuf[2 * CGR];   // 30 KB: two 6-slab f16 chunks, LINEAR

  const int tid  = threadIdx.x;
  const int wave = tid >> 6;
  const int lane = tid & 63;
  const int bq   = lane & 15;
  const int og   = lane >> 4;
  const bool lo32 = (lane < 32);
  const int og8  = (og & 1) * 8;          // byte offset of this lane's 8B k-slice

  const int bid   = blockIdx.x;
  const int xcd   = bid & 7;
  const int idx   = bid >> 3;             // 0..63
  const int rtile = xcd * 8 + (idx & 7);
  const int btile = idx >> 3;             // 0..7

  const int b  = btile * 64 + wave * 16 + bq;
  const int r0 = rtile * RCHB;

  // linear staging: chunk rows are contiguous in W (6 consecutive r slabs)
  auto stage = [&](int ci, int buf) {
    const int rbase = r0 + ci * CHUNK;
    #pragma unroll 1
    for (int g = tid; g < CGR; g += 256) {
      const float4* wsrc = reinterpret_cast<const float4*>(W)
                         + ((size_t)rbase * ROWS + g) * 2;
      const float4 a = wsrc[0], c4 = wsrc[1];
      uint4 v;
      v.x = packf2(a.x, a.y);  v.y = packf2(a.z, a.w);
      v.z = packf2(c4.x, c4.y); v.w = packf2(c4.z, c4.w);
      wbuf[buf * CGR + g] = v;
    }
  };

  // x fragment: lanes 0-31 carry the real k-slice (8B of xt row), rest zero
  auto xload = [&](int r) -> uint2 {
    uint2 v; v.x = 0u; v.y = 0u;
    if (lo32)
      v = *reinterpret_cast<const uint2*>(
          reinterpret_cast<const char*>(xt + (size_t)r * B_TOT + b) + og8);
    return v;
  };

  float vf[C_N][4];
  if constexpr (!UNIFORM) {
    #pragma unroll
    for (int c = 0; c < C_N; ++c) {
      const float4 tv = *reinterpret_cast<const float4*>(
          &vsum[((size_t)b * C_N + c) * O_N + og * 4]);
      vf[c][0] = tv.x; vf[c][1] = tv.y; vf[c][2] = tv.z; vf[c][3] = tv.w;
    }
  }

  float sacc[C_N][4];
  #pragma unroll
  for (int c = 0; c < C_N; ++c)
    #pragma unroll
    for (int j = 0; j < 4; ++j) sacc[c][j] = 0.0f;

  uint2 xc, xn;
  stage(0, 0);
  xc = xload(r0);
  __syncthreads();

  #pragma unroll 1
  for (int ci = 0; ci < NCH; ++ci) {
    if (ci + 1 < NCH) stage(ci + 1, (ci + 1) & 1);
    const int sb = (ci & 1) * CGR;
    #pragma unroll 1
    for (int rr = 0; rr < CHUNK; ++rr) {
      const int rl = ci * CHUNK + rr;
      const int rn = (rl + 1 < RCHB) ? rl + 1 : rl;
      xn = xload(r0 + rn);                // prefetch next x under compute

      // ---- MFMA einsum: u[c][j] for this lane's (b, og) ----
      u32x4 bxv = {xc.x, xc.y, 0u, 0u};   // B frag: k-slice in regs0-1, rest 0
      const v8h bf = __builtin_bit_cast(v8h, bxv);
      const char* wb = reinterpret_cast<const char*>(&wbuf[sb + rr * ROWS]);

      float u[C_N][4];
      #pragma unroll
      for (int cg = 0; cg < 2; ++cg) {
        uint2 w8[5];
        #pragma unroll
        for (int c5 = 0; c5 < 5; ++c5) { w8[c5].x = 0u; w8[c5].y = 0u; }
        if (lo32) {
          #pragma unroll
          for (int c5 = 0; c5 < 5; ++c5) {
            const int c = cg * 5 + c5;
            w8[c5] = *reinterpret_cast<const uint2*>(
                wb + (c * 16 + bq) * 16 + og8);
          }
        }
        #pragma unroll
        for (int c5 = 0; c5 < 5; ++c5) {
          u32x4 axv = {w8[c5].x, w8[c5].y, 0u, 0u};
          v4f d = __builtin_amdgcn_mfma_f32_16x16x32_f16(
              __builtin_bit_cast(v8h, axv), bf,
              (v4f){0.f, 0.f, 0.f, 0.f}, 0, 0, 0);
          const int c = cg * 5 + c5;
          u[c][0] = d[0]; u[c][1] = d[1]; u[c][2] = d[2]; u[c][3] = d[3];
        }
      }

      // ---- routing update ----
      if constexpr (UNIFORM) {
        #pragma unroll
        for (int c = 0; c < C_N; ++c)
          #pragma unroll
          for (int j = 0; j < 4; ++j) sacc[c][j] += u[c][j];
      } else {
        float bij[C_N];
        #pragma unroll
        for (int c = 0; c < C_N; ++c) {
          float a = u[c][0] * vf[c][0] + u[c][1] * vf[c][1]
                  + u[c][2] * vf[c][2] + u[c][3] * vf[c][3];
          a += __shfl_xor(a, 16);         // combine og pairs
          a += __shfl_xor(a, 32);         // combine all 4 og
          bij[c] = a;
        }
        float m = bij[0];
        #pragma unroll
        for (int c = 1; c < C_N; ++c) m = fmaxf(m, bij[c]);
        float e[C_N];
        float den = 0.0f;
        #pragma unroll
        for (int c = 0; c < C_N; ++c) { e[c] = __expf(bij[c] - m); den += e[c]; }
        const float inv = __builtin_amdgcn_rcpf(den);
        #pragma unroll
        for (int c = 0; c < C_N; ++c) {
          const float cw = e[c] * inv;
          #pragma unroll
          for (int j = 0; j < 4; ++j) sacc[c][j] += cw * u[c][j];
        }
      }
      xc = xn;
    }
    __syncthreads();
  }

  const float scale = UNIFORM ? 0.1f : 1.0f;
  float* pb = part + (size_t)rtile * SEG;
  #pragma unroll
  for (int c = 0; c < C_N; ++c) {
    float4 v;
    v.x = sacc[c][0] * scale; v.y = sacc[c][1] * scale;
    v.z = sacc[c][2] * scale; v.w = sacc[c][3] * scale;
    *reinterpret_cast<float4*>(
        &pb[((size_t)b * C_N + c) * O_N + og * 4]) = v;
  }
}

// reduce over rtiles + squash over O=16 per (b,c). grid = SEG/64 blocks.
// MODE 0: vsum = v ; MODE 1: vsum += v ; MODE 2: out = v
template<int MODE>
__global__ __launch_bounds__(256) void reduce_squash(
    const float* __restrict__ part, int nrt,
    float* __restrict__ vsum, float* __restrict__ out)
{
  __shared__ float lds[4][64];
  const int tid = threadIdx.x;
  const int l   = tid & 63;
  const int q   = tid >> 6;
  const int j   = blockIdx.x * 64 + l;
  const float* p = part + j;
  float sv = 0.0f;
  #pragma unroll 4
  for (int rt = q; rt < nrt; rt += 4) sv += p[(size_t)rt * SEG];
  lds[q][l] = sv;
  __syncthreads();
  if (q == 0) {
    sv = lds[0][l] + lds[1][l] + lds[2][l] + lds[3][l];
    float sq = sv * sv;
    sq += __shfl_xor(sq, 1);
    sq += __shfl_xor(sq, 2);
    sq += __shfl_xor(sq, 4);
    sq += __shfl_xor(sq, 8);
    const float scale = sq / (1.0f + sq) * rsqrtf(sq + 1e-8f);
    const float v = scale * sv;
    if constexpr (MODE == 0)      vsum[j] = v;
    else if constexpr (MODE == 1) vsum[j] += v;
    else                          out[j] = v;
  }
}

extern "C" void kernel_launch(void* const* d_in, const int* in_sizes, int n_in,
                              void* d_out, int out_size, void* d_ws, size_t ws_size,
                              hipStream_t stream) {
  (void)in_sizes; (void)n_in; (void)out_size; (void)ws_size;
  const float* x = (const float*)d_in[0];
  const float* W = (const float*)d_in[1];
  float* out  = (float*)d_out;   // doubles as vsum; fully rewritten with v2
  float* part = (float*)d_ws;    // RT * SEG floats = 21 MB
  uint4* xt   = reinterpret_cast<uint4*>(part + (size_t)RT * SEG);  // 9.4 MB f16

  const dim3 blk(256), accGrid(8 * RT), sqGrid(SEG / 64);

  hipLaunchKernelGGL(transpose_x, dim3((B_TOT * R_TOT) / 256), blk, 0, stream, x, xt);

  // iter 0: uniform coefficients (softmax of zeros)
  hipLaunchKernelGGL((acc_kernel<true>),  accGrid, blk, 0, stream, xt, W, out, part);
  hipLaunchKernelGGL((reduce_squash<0>),  sqGrid,  blk, 0, stream, part, RT, out, out);  // vsum = v0
  // iter 1
  hipLaunchKernelGGL((acc_kernel<false>), accGrid, blk, 0, stream, xt, W, out, part);
  hipLaunchKernelGGL((reduce_squash<1>),  sqGrid,  blk, 0, stream, part, RT, out, out);  // vsum = v0+v1
  // iter 2
  hipLaunchKernelGGL((acc_kernel<false>), accGrid, blk, 0, stream, xt, W, out, part);
  hipLaunchKernelGGL((reduce_squash<2>),  sqGrid,  blk, 0, stream, part, RT, out, out);  // out = v2
}